// Round 1
// baseline (4274.702 us; speedup 1.0000x reference)
//
#include <hip/hip_runtime.h>
#include <cfloat>
#include <cmath>

#define B_ 4
#define N_ 16384
#define M_ 512
#define C_ 128
#define K_ 16
#define L_ 6
#define STEPS_ 5

// ---------------- wave helpers (wave64) ----------------
__device__ inline unsigned long long wave_min_u64(unsigned long long v) {
#pragma unroll
  for (int m = 1; m < 64; m <<= 1) {
    unsigned long long o = __shfl_xor(v, m, 64);
    v = (o < v) ? o : v;
  }
  return v;
}
__device__ inline float wave_sum(float v) {
#pragma unroll
  for (int m = 1; m < 64; m <<= 1) v += __shfl_xor(v, m, 64);
  return v;
}

// ---------------- encoder: feats = lin2(relu(lin1(xyz))) ----------------
// 32 points per block, 256 threads, w2 staged in LDS.
__global__ __launch_bounds__(256) void k_encode(
    const float* __restrict__ xyz, const float* __restrict__ w1,
    const float* __restrict__ b1, const float* __restrict__ w2,
    const float* __restrict__ b2, float* __restrict__ feats) {
  __shared__ __align__(16) float s_w2[128 * 64];
  __shared__ __align__(16) float s_xyz[32 * 3];
  __shared__ __align__(16) float s_h[32 * 64];
  int t = threadIdx.x;
  for (int i = t; i < 128 * 64 / 4; i += 256)
    ((float4*)s_w2)[i] = ((const float4*)w2)[i];
  int p0 = blockIdx.x * 32;
  for (int i = t; i < 96; i += 256) s_xyz[i] = xyz[(size_t)p0 * 3 + i];
  __syncthreads();
  int p = t >> 3, q = t & 7;
  float x0 = s_xyz[p * 3], x1 = s_xyz[p * 3 + 1], x2 = s_xyz[p * 3 + 2];
#pragma unroll
  for (int cc = 0; cc < 8; ++cc) {
    int c = q * 8 + cc;
    float a = b1[c] + w1[c * 3] * x0 + w1[c * 3 + 1] * x1 + w1[c * 3 + 2] * x2;
    s_h[p * 64 + c] = fmaxf(a, 0.f);
  }
  __syncthreads();
#pragma unroll
  for (int cc = 0; cc < 16; ++cc) {
    int c = q * 16 + cc;
    float acc = b2[c];
    const float* wr = &s_w2[c * 64];
    const float* hr = &s_h[p * 64];
#pragma unroll
    for (int j = 0; j < 64; j += 4) {
      float4 w4 = *(const float4*)&wr[j];
      float4 h4 = *(const float4*)&hr[j];
      acc += w4.x * h4.x + w4.y * h4.y + w4.z * h4.z + w4.w * h4.w;
    }
    feats[(size_t)(p0 + p) * 128 + c] = acc;
  }
}

// ---------------- per-step init: idx = start, walks row0 = feats[start] -----
__global__ __launch_bounds__(128) void k_step_init(
    const float* __restrict__ feats, const int* __restrict__ start,
    int* __restrict__ idxbuf, float* __restrict__ walks) {
  int g = blockIdx.x;
  int c = threadIdx.x;
  int b = g >> 9;
  int s = start[g];
  walks[(size_t)g * 768 + c] = feats[((size_t)b * N_ + s) * 128 + c];
  if (c == 0) idxbuf[g] = s;
}

// ---------------- selector round: exact 17-NN + gumbel argmax --------------
// one wave (64 threads) per walker; 2048 blocks.
__global__ __launch_bounds__(64) void k_select(
    const float* __restrict__ pos, const float* __restrict__ feats,
    int* __restrict__ idxbuf, float* __restrict__ walks,
    const float* __restrict__ beta_w, const float* __restrict__ beta_b,
    const float* __restrict__ gamma_w, const float* __restrict__ gamma_b,
    const float* __restrict__ gumb, int l) {
  __shared__ __align__(16) float s_f[128];
  __shared__ __align__(16) float s_q[128];
  __shared__ unsigned int s_knn[17];
  __shared__ unsigned long long s_cand[128];
  __shared__ int s_cnt;

  int g = blockIdx.x;
  int lane = threadIdx.x;
  int b = g >> 9, mm = g & (M_ - 1);
  int idx0 = idxbuf[g];

  const float* fi = feats + ((size_t)b * N_ + idx0) * 128;
  s_f[lane] = fi[lane];
  s_f[lane + 64] = fi[lane + 64];
  if (lane == 0) s_cnt = 0;
  __syncthreads();

  // q = beta_w @ f_i + beta_b  (lane handles c = lane, lane+64)
  float aq0 = beta_b[lane], aq1 = beta_b[lane + 64];
#pragma unroll 4
  for (int j = 0; j < 128; j += 4) {
    float4 w0 = *(const float4*)&beta_w[(size_t)lane * 128 + j];
    float4 w1 = *(const float4*)&beta_w[(size_t)(lane + 64) * 128 + j];
    float4 f4 = *(const float4*)&s_f[j];
    aq0 += w0.x * f4.x + w0.y * f4.y + w0.z * f4.z + w0.w * f4.w;
    aq1 += w1.x * f4.x + w1.y * f4.y + w1.z * f4.z + w1.w * f4.w;
  }
  s_q[lane] = aq0;
  s_q[lane + 64] = aq1;
  __syncthreads();

  // qg = gamma_w^T @ q ; qb = q . gamma_b
  float g0 = 0.f, g1 = 0.f;
  float qbp = s_q[lane] * gamma_b[lane] + s_q[lane + 64] * gamma_b[lane + 64];
#pragma unroll 4
  for (int c = 0; c < 128; ++c) {
    float qc = s_q[c];
    g0 += qc * gamma_w[(size_t)c * 128 + lane];
    g1 += qc * gamma_w[(size_t)c * 128 + lane + 64];
  }
  float qb = wave_sum(qbp);

  const float* pp = pos + ((size_t)b * N_ + idx0) * 3;
  float qx = pp[0], qy = pp[1], qz = pp[2];
  const float* pb = pos + (size_t)b * N_ * 3;

  // pass 1: per-lane min (d2, idx)
  float best = FLT_MAX;
  int bi = 0;
  {
#pragma clang fp contract(off)
    for (int j = lane; j < N_; j += 64) {
      float dx = pb[3 * j] - qx;
      float dy = pb[3 * j + 1] - qy;
      float dz = pb[3 * j + 2] - qz;
      float xx = dx * dx;
      float yy = dy * dy;
      float zz = dz * dz;
      float d2 = (xx + yy) + zz;
      if (d2 < best) { best = d2; bi = j; }
    }
  }
  unsigned long long key =
      ((unsigned long long)__float_as_uint(best) << 32) | (unsigned)bi;
  // tau = 17th smallest of the 64 lane minima (valid upper bound on global 17th)
  unsigned long long cur = key, kth = 0;
  for (int it = 0; it < 17; ++it) {
    unsigned long long mn = wave_min_u64(cur);
    kth = mn;
    if (cur == mn) cur = ~0ULL;
  }
  float tau = __uint_as_float((unsigned)(kth >> 32));

  // pass 2: collect all points with d2 <= tau (superset of exact top-17)
  {
#pragma clang fp contract(off)
    for (int j = lane; j < N_; j += 64) {
      float dx = pb[3 * j] - qx;
      float dy = pb[3 * j + 1] - qy;
      float dz = pb[3 * j + 2] - qz;
      float xx = dx * dx;
      float yy = dy * dy;
      float zz = dz * dz;
      float d2 = (xx + yy) + zz;
      if (d2 <= tau) {
        int p = atomicAdd(&s_cnt, 1);
        if (p < 128)
          s_cand[p] =
              ((unsigned long long)__float_as_uint(d2) << 32) | (unsigned)j;
      }
    }
  }
  __syncthreads();
  int cnt = s_cnt;
  if (cnt > 128) cnt = 128;
  unsigned long long c0 = (lane < cnt) ? s_cand[lane] : ~0ULL;
  unsigned long long c1 = (lane + 64 < cnt) ? s_cand[lane + 64] : ~0ULL;
  for (int it = 0; it < 17; ++it) {
    unsigned long long lo = (c0 < c1) ? c0 : c1;
    unsigned long long mn = wave_min_u64(lo);
    if (lane == 0) s_knn[it] = (unsigned)mn;
    if (c0 == mn) c0 = ~0ULL;
    else if (c1 == mn) c1 = ~0ULL;
  }
  __syncthreads();

  // gather 16 neighbor feature fragments (batched loads to hide latency)
  float f0[16], f1[16];
#pragma unroll
  for (int k = 0; k < 16; ++k) {
    unsigned nb = s_knn[k + 1];
    const float* fp = feats + ((size_t)b * N_ + nb) * 128;
    f0[k] = fp[lane];
    f1[k] = fp[lane + 64];
  }
  const float* gbp = gumb + (((size_t)b) * M_ + mm) * K_;
  float bestv = -FLT_MAX;
  unsigned bestn = s_knn[1];
#pragma unroll
  for (int k = 0; k < 16; ++k) {
    float pr = g0 * f0[k] + g1 * f1[k];
    float ssum = wave_sum(pr);
    float logit = (ssum + qb) / sqrtf(128.0f);
    float tot = (logit + gbp[k]) / 0.1f;
    if (tot > bestv) { bestv = tot; bestn = s_knn[k + 1]; }
  }

  const float* fnp = feats + ((size_t)b * N_ + bestn) * 128;
  walks[(size_t)g * 768 + (size_t)(l + 1) * 128 + lane] = fnp[lane];
  walks[(size_t)g * 768 + (size_t)(l + 1) * 128 + lane + 64] = fnp[lane + 64];
  if (lane == 0) idxbuf[g] = (int)bestn;
}

// ---------------- route + predict + scatter (one block per walker) ----------
__global__ __launch_bounds__(128) void k_route(
    const float* __restrict__ curr, const float* __restrict__ prev,
    float* __restrict__ outw, const float* __restrict__ w_in,
    const float* __restrict__ b_in, const float* __restrict__ w_out,
    const float* __restrict__ b_out, const float* __restrict__ rt_w1,
    const float* __restrict__ rt_b1, const float* __restrict__ rt_w2,
    const float* __restrict__ rt_b2, const float* __restrict__ pw1,
    const float* __restrict__ pb1, const float* __restrict__ pw2,
    const float* __restrict__ pb2, const int* __restrict__ start,
    float* __restrict__ pos) {
  __shared__ __align__(16) float s_c[768];
  __shared__ __align__(16) float s_p[768];
  __shared__ __align__(16) float s_q[768];
  __shared__ __align__(16) float s_k[768];
  __shared__ __align__(16) float s_v[768];
  __shared__ __align__(16) float s_o[768];
  __shared__ __align__(16) float s_t2[768];
  __shared__ __align__(16) float s_att[144];
  __shared__ __align__(16) float s_x[256];
  __shared__ __align__(16) float s_hid[64];

  int g = blockIdx.x, t = threadIdx.x;
  int b = g >> 9;
  const float* cg = curr + (size_t)g * 768;
  const float* pg = prev + (size_t)g * 768;
  for (int i = t; i < 768; i += 128) {
    s_c[i] = cg[i];
    s_p[i] = pg[i];
  }
  __syncthreads();

  // QKV (thread t owns channel t across all 6 rows)
  float aq[6], ak[6], av[6];
#pragma unroll
  for (int l = 0; l < 6; ++l) {
    aq[l] = b_in[t];
    ak[l] = b_in[128 + t];
    av[l] = b_in[256 + t];
  }
  for (int j = 0; j < 128; j += 4) {
    float4 wq = *(const float4*)&w_in[(size_t)t * 128 + j];
    float4 wk = *(const float4*)&w_in[(size_t)(128 + t) * 128 + j];
    float4 wv = *(const float4*)&w_in[(size_t)(256 + t) * 128 + j];
#pragma unroll
    for (int l = 0; l < 6; ++l) {
      float4 c4 = *(const float4*)&s_c[l * 128 + j];
      float4 p4 = *(const float4*)&s_p[l * 128 + j];
      aq[l] += wq.x * c4.x + wq.y * c4.y + wq.z * c4.z + wq.w * c4.w;
      ak[l] += wk.x * p4.x + wk.y * p4.y + wk.z * p4.z + wk.w * p4.w;
      av[l] += wv.x * p4.x + wv.y * p4.y + wv.z * p4.z + wv.w * p4.w;
    }
  }
#pragma unroll
  for (int l = 0; l < 6; ++l) {
    s_q[l * 128 + t] = aq[l];
    s_k[l * 128 + t] = ak[l];
    s_v[l * 128 + t] = av[l];
  }
  __syncthreads();

  // scores
  for (int e = t; e < 144; e += 128) {
    int h = e / 36, r = e % 36, i = r / 6, jj = r % 6;
    float acc = 0.f;
#pragma unroll
    for (int d = 0; d < 32; d += 4) {
      float4 q4 = *(const float4*)&s_q[i * 128 + h * 32 + d];
      float4 k4 = *(const float4*)&s_k[jj * 128 + h * 32 + d];
      acc += q4.x * k4.x + q4.y * k4.y + q4.z * k4.z + q4.w * k4.w;
    }
    s_att[e] = acc / sqrtf(32.0f);
  }
  __syncthreads();
  // softmax over k for each of 24 (h,i) rows
  if (t < 24) {
    int h = t / 6, i = t % 6;
    int base = h * 36 + i * 6;
    float mx = s_att[base];
#pragma unroll
    for (int jj = 1; jj < 6; ++jj) mx = fmaxf(mx, s_att[base + jj]);
    float ex[6];
    float sum = 0.f;
#pragma unroll
    for (int jj = 0; jj < 6; ++jj) {
      ex[jj] = expf(s_att[base + jj] - mx);
      sum += ex[jj];
    }
#pragma unroll
    for (int jj = 0; jj < 6; ++jj) s_att[base + jj] = ex[jj] / sum;
  }
  __syncthreads();
  // attn @ V
  {
    int h = t >> 5;
    float o[6];
#pragma unroll
    for (int l = 0; l < 6; ++l) {
      float acc = 0.f;
#pragma unroll
      for (int jj = 0; jj < 6; ++jj)
        acc += s_att[h * 36 + l * 6 + jj] * s_v[jj * 128 + t];
      o[l] = acc;
    }
#pragma unroll
    for (int l = 0; l < 6; ++l) s_o[l * 128 + t] = o[l];
  }
  __syncthreads();

  // out-proj -> s_q (reuse)
  float ao[6];
#pragma unroll
  for (int l = 0; l < 6; ++l) ao[l] = b_out[t];
  for (int j = 0; j < 128; j += 4) {
    float4 w4 = *(const float4*)&w_out[(size_t)t * 128 + j];
#pragma unroll
    for (int l = 0; l < 6; ++l) {
      float4 o4 = *(const float4*)&s_o[l * 128 + j];
      ao[l] += w4.x * o4.x + w4.y * o4.y + w4.z * o4.z + w4.w * o4.w;
    }
  }
  __syncthreads();
#pragma unroll
  for (int l = 0; l < 6; ++l) s_q[l * 128 + t] = ao[l];
  __syncthreads();

  // rt1 + relu -> s_t2
  float a1[6];
#pragma unroll
  for (int l = 0; l < 6; ++l) a1[l] = rt_b1[t];
  for (int j = 0; j < 128; j += 4) {
    float4 w4 = *(const float4*)&rt_w1[(size_t)t * 128 + j];
#pragma unroll
    for (int l = 0; l < 6; ++l) {
      float4 o4 = *(const float4*)&s_q[l * 128 + j];
      a1[l] += w4.x * o4.x + w4.y * o4.y + w4.z * o4.z + w4.w * o4.w;
    }
  }
#pragma unroll
  for (int l = 0; l < 6; ++l) s_t2[l * 128 + t] = fmaxf(a1[l], 0.f);
  __syncthreads();

  // rt2 -> o3 (global + s_c reuse)
  float a2[6];
#pragma unroll
  for (int l = 0; l < 6; ++l) a2[l] = rt_b2[t];
  for (int j = 0; j < 128; j += 4) {
    float4 w4 = *(const float4*)&rt_w2[(size_t)t * 128 + j];
#pragma unroll
    for (int l = 0; l < 6; ++l) {
      float4 o4 = *(const float4*)&s_t2[l * 128 + j];
      a2[l] += w4.x * o4.x + w4.y * o4.y + w4.z * o4.z + w4.w * o4.w;
    }
  }
  __syncthreads();
  float* og = outw + (size_t)g * 768;
#pragma unroll
  for (int l = 0; l < 6; ++l) {
    og[l * 128 + t] = a2[l];
    s_c[l * 128 + t] = a2[l];
  }
  __syncthreads();

  // predict: x = [mean(rel), central]
  {
    float sm = 0.f;
#pragma unroll
    for (int l = 1; l < 6; ++l) sm += s_c[l * 128 + t];
    s_x[t] = sm / 5.0f - s_c[t];
    s_x[128 + t] = s_c[t];
  }
  __syncthreads();
  if (t < 64) {
    float acc = pb1[t];
#pragma unroll
    for (int j = 0; j < 256; j += 4) {
      float4 w4 = *(const float4*)&pw1[(size_t)t * 256 + j];
      float4 x4 = *(const float4*)&s_x[j];
      acc += w4.x * x4.x + w4.y * x4.y + w4.z * x4.z + w4.w * x4.w;
    }
    s_hid[t] = fmaxf(acc, 0.f);
  }
  __syncthreads();
  if (t < 3) {
    float acc = pb2[t];
#pragma unroll
    for (int j = 0; j < 64; ++j) acc += pw2[t * 64 + j] * s_hid[j];
    float d = tanhf(acc);
    int s = start[g];
    atomicAdd(&pos[((size_t)b * N_ + s) * 3 + t], d);
  }
}

// ---------------- launcher ----------------
extern "C" void kernel_launch(void* const* d_in, const int* in_sizes, int n_in,
                              void* d_out, int out_size, void* d_ws,
                              size_t ws_size, hipStream_t stream) {
  const float* xyz = (const float*)d_in[0];
  const int* start = (const int*)d_in[1];
  const float* gumbel = (const float*)d_in[2];
  const float* enc_w1 = (const float*)d_in[3];
  const float* enc_b1 = (const float*)d_in[4];
  const float* enc_w2 = (const float*)d_in[5];
  const float* enc_b2 = (const float*)d_in[6];
  const float* beta_w = (const float*)d_in[7];
  const float* beta_b = (const float*)d_in[8];
  const float* gamma_w = (const float*)d_in[9];
  const float* gamma_b = (const float*)d_in[10];
  const float* attn_w_in = (const float*)d_in[11];
  const float* attn_b_in = (const float*)d_in[12];
  const float* attn_w_out = (const float*)d_in[13];
  const float* attn_b_out = (const float*)d_in[14];
  const float* rt_w1 = (const float*)d_in[15];
  const float* rt_b1 = (const float*)d_in[16];
  const float* rt_w2 = (const float*)d_in[17];
  const float* rt_b2 = (const float*)d_in[18];
  const float* pred_w1 = (const float*)d_in[19];
  const float* pred_b1 = (const float*)d_in[20];
  const float* pred_w2 = (const float*)d_in[21];
  const float* pred_b2 = (const float*)d_in[22];

  float* pos = (float*)d_out;
  float* ws = (float*)d_ws;
  float* feats = ws;                                   // 4*16384*128 f32 (32MB)
  float* wsel = feats + (size_t)B_ * N_ * C_;          // 6MB
  float* wA = wsel + (size_t)B_ * M_ * L_ * C_;        // 6MB
  float* wB = wA + (size_t)B_ * M_ * L_ * C_;          // 6MB
  int* idxbuf = (int*)(wB + (size_t)B_ * M_ * L_ * C_);

  hipMemcpyAsync(pos, xyz, (size_t)B_ * N_ * 3 * sizeof(float),
                 hipMemcpyDeviceToDevice, stream);
  k_encode<<<2048, 256, 0, stream>>>(xyz, enc_w1, enc_b1, enc_w2, enc_b2,
                                     feats);

  float* prevbuf = wsel;
  for (int t = 0; t < STEPS_; ++t) {
    k_step_init<<<2048, 128, 0, stream>>>(feats, start, idxbuf, wsel);
    for (int l = 0; l < L_ - 1; ++l) {
      const float* gptr =
          gumbel + (size_t)(t * (L_ - 1) + l) * B_ * M_ * K_;
      k_select<<<2048, 64, 0, stream>>>(pos, feats, idxbuf, wsel, beta_w,
                                        beta_b, gamma_w, gamma_b, gptr, l);
    }
    float* ob = (t & 1) ? wB : wA;
    k_route<<<2048, 128, 0, stream>>>(
        wsel, prevbuf, ob, attn_w_in, attn_b_in, attn_w_out, attn_b_out, rt_w1,
        rt_b1, rt_w2, rt_b2, pred_w1, pred_b1, pred_w2, pred_b2, start, pos);
    prevbuf = ob;
  }
}

// Round 2
// 2613.715 us; speedup vs baseline: 1.6355x; 1.6355x over previous
//
#include <hip/hip_runtime.h>
#include <cfloat>
#include <cmath>

#define B_ 4
#define N_ 16384
#define M_ 512
#define C_ 128
#define K_ 16
#define L_ 6
#define STEPS_ 5

// ---------------- wave helpers (wave64) ----------------
__device__ inline unsigned long long wave_min_u64(unsigned long long v) {
#pragma unroll
  for (int m = 1; m < 64; m <<= 1) {
    unsigned long long o = __shfl_xor(v, m, 64);
    v = (o < v) ? o : v;
  }
  return v;
}
__device__ inline float wave_sum(float v) {
#pragma unroll
  for (int m = 1; m < 64; m <<= 1) v += __shfl_xor(v, m, 64);
  return v;
}

// ---------------- encoder: feats = lin2(relu(lin1(xyz))) ----------------
// 32 points per block, 256 threads. LDS strides padded to 68 floats so rows
// land on distinct bank groups (was 64 -> 8-way conflicts, 7e7 cycles).
__global__ __launch_bounds__(256) void k_encode(
    const float* __restrict__ xyz, const float* __restrict__ w1,
    const float* __restrict__ b1, const float* __restrict__ w2,
    const float* __restrict__ b2, float* __restrict__ feats) {
  __shared__ __align__(16) float s_w2[128 * 68];
  __shared__ __align__(16) float s_xyz[32 * 3];
  __shared__ __align__(16) float s_h[32 * 68];
  int t = threadIdx.x;
  for (int i = t; i < 128 * 64; i += 256) {
    int c = i >> 6, j = i & 63;
    s_w2[c * 68 + j] = w2[i];
  }
  int p0 = blockIdx.x * 32;
  for (int i = t; i < 96; i += 256) s_xyz[i] = xyz[(size_t)p0 * 3 + i];
  __syncthreads();
  int p = t >> 3, q = t & 7;
  float x0 = s_xyz[p * 3], x1 = s_xyz[p * 3 + 1], x2 = s_xyz[p * 3 + 2];
#pragma unroll
  for (int cc = 0; cc < 8; ++cc) {
    int c = q * 8 + cc;
    float a = b1[c] + w1[c * 3] * x0 + w1[c * 3 + 1] * x1 + w1[c * 3 + 2] * x2;
    s_h[p * 68 + c] = fmaxf(a, 0.f);
  }
  __syncthreads();
#pragma unroll
  for (int cc = 0; cc < 16; ++cc) {
    int c = q + cc * 8;  // bank-friendly: addr word = 68c+j -> (4q+j)%32
    float acc = b2[c];
    const float* wr = &s_w2[c * 68];
    const float* hr = &s_h[p * 68];
#pragma unroll
    for (int j = 0; j < 64; j += 4) {
      float4 w4 = *(const float4*)&wr[j];
      float4 h4 = *(const float4*)&hr[j];
      acc += w4.x * h4.x + w4.y * h4.y + w4.z * h4.z + w4.w * h4.w;
    }
    feats[(size_t)(p0 + p) * 128 + c] = acc;
  }
}

// ---------------- per-step init ----------------
__global__ __launch_bounds__(128) void k_step_init(
    const float* __restrict__ feats, const int* __restrict__ start,
    int* __restrict__ idxbuf, float* __restrict__ walks) {
  int g = blockIdx.x;
  int c = threadIdx.x;
  int b = g >> 9;
  int s = start[g];
  walks[(size_t)g * 768 + c] = feats[((size_t)b * N_ + s) * 128 + c];
  if (c == 0) idxbuf[g] = s;
}

// ---------------- selector round: exact 17-NN + gumbel argmax --------------
// 256 threads (4 waves) per walker; each wave scans N/4 points.
#define D2_BLOCK(PX, PY, PZ, JIDX)                        \
  {                                                       \
    float dx = (PX)-qx, dy = (PY)-qy, dz = (PZ)-qz;       \
    float xx = dx * dx, yy = dy * dy, zz = dz * dz;       \
    float d2 = (xx + yy) + zz;                            \
    if (d2 < best) { best = d2; bi = (JIDX); }            \
  }
#define D2_PUSH(PX, PY, PZ, JIDX)                                         \
  {                                                                       \
    float dx = (PX)-qx, dy = (PY)-qy, dz = (PZ)-qz;                       \
    float xx = dx * dx, yy = dy * dy, zz = dz * dz;                       \
    float d2 = (xx + yy) + zz;                                            \
    if (d2 <= tau) {                                                      \
      int p = atomicAdd(&s_cnt, 1);                                       \
      if (p < 192)                                                        \
        s_cand[p] = ((unsigned long long)__float_as_uint(d2) << 32) |     \
                    (unsigned)(JIDX);                                     \
    }                                                                     \
  }

__global__ __launch_bounds__(256) void k_select(
    const float* __restrict__ pos, const float* __restrict__ feats,
    int* __restrict__ idxbuf, float* __restrict__ walks,
    const float* __restrict__ beta_w, const float* __restrict__ beta_b,
    const float* __restrict__ gamma_w, const float* __restrict__ gamma_b,
    const float* __restrict__ gumb, int l) {
  __shared__ __align__(16) float s_f[128];
  __shared__ __align__(16) float s_q[128];
  __shared__ __align__(16) float s_g[128];
  __shared__ float s_qb;
  __shared__ float s_tau;
  __shared__ float s_logit[16];
  __shared__ unsigned long long s_keys[256];
  __shared__ unsigned long long s_cand[192];
  __shared__ unsigned int s_knn[17];
  __shared__ int s_cnt;
  __shared__ int s_bestn;

  int g = blockIdx.x, t = threadIdx.x;
  int lane = t & 63, w = t >> 6;
  int b = g >> 9, mm = g & (M_ - 1);
  int idx0 = idxbuf[g];
  if (t < 128) s_f[t] = feats[((size_t)b * N_ + idx0) * 128 + t];
  if (t == 0) s_cnt = 0;
  __syncthreads();

  // q = beta_w @ f_i + beta_b (threads 0..127, one channel each)
  if (t < 128) {
    float aq = beta_b[t];
#pragma unroll 4
    for (int j = 0; j < 128; j += 4) {
      float4 w4 = *(const float4*)&beta_w[(size_t)t * 128 + j];
      float4 f4 = *(const float4*)&s_f[j];
      aq += w4.x * f4.x + w4.y * f4.y + w4.z * f4.z + w4.w * f4.w;
    }
    s_q[t] = aq;
  }
  __syncthreads();
  // g = gamma_w^T @ q (coalesced column reads); qb = q . gamma_b (wave 0)
  if (t < 128) {
    float gg = 0.f;
    for (int cidx = 0; cidx < 128; ++cidx)
      gg += s_q[cidx] * gamma_w[(size_t)cidx * 128 + t];
    s_g[t] = gg;
  }
  if (w == 0) {
    float qbp = s_q[lane] * gamma_b[lane] + s_q[lane + 64] * gamma_b[lane + 64];
    float qb = wave_sum(qbp);
    if (lane == 0) s_qb = qb;
  }

  const float* pp = pos + ((size_t)b * N_ + idx0) * 3;
  float qx = pp[0], qy = pp[1], qz = pp[2];
  const float* pb = pos + (size_t)b * N_ * 3;

  // pass 1: per-thread min over this thread's 256 points (4 per iter)
  float best = FLT_MAX;
  int bi = 0;
  {
#pragma clang fp contract(off)
    for (int it = 0; it < 16; ++it) {
      int j0 = w * 4096 + (it * 64 + lane) * 4;
      float4 p0 = *(const float4*)&pb[3 * j0];
      float4 p1 = *(const float4*)&pb[3 * j0 + 4];
      float4 p2 = *(const float4*)&pb[3 * j0 + 8];
      D2_BLOCK(p0.x, p0.y, p0.z, j0)
      D2_BLOCK(p0.w, p1.x, p1.y, j0 + 1)
      D2_BLOCK(p1.z, p1.w, p2.x, j0 + 2)
      D2_BLOCK(p2.y, p2.z, p2.w, j0 + 3)
    }
  }
  s_keys[t] = ((unsigned long long)__float_as_uint(best) << 32) | (unsigned)bi;
  __syncthreads();
  // tau = 17th smallest of 256 thread minima (upper bound on exact 17th-NN:
  // the 17 holders own >=17 distinct points <= tau)
  if (w == 0) {
    unsigned long long c0 = s_keys[lane], c1 = s_keys[lane + 64];
    unsigned long long c2 = s_keys[lane + 128], c3 = s_keys[lane + 192];
    unsigned long long kth = 0;
    for (int it = 0; it < 17; ++it) {
      unsigned long long l01 = c0 < c1 ? c0 : c1;
      unsigned long long l23 = c2 < c3 ? c2 : c3;
      unsigned long long lo = l01 < l23 ? l01 : l23;
      unsigned long long mn = wave_min_u64(lo);
      kth = mn;
      if (c0 == mn) c0 = ~0ULL;
      else if (c1 == mn) c1 = ~0ULL;
      else if (c2 == mn) c2 = ~0ULL;
      else if (c3 == mn) c3 = ~0ULL;
    }
    if (lane == 0) s_tau = __uint_as_float((unsigned)(kth >> 32));
  }
  __syncthreads();
  float tau = s_tau;

  // pass 2: collect candidates <= tau (superset of exact top-17)
  {
#pragma clang fp contract(off)
    for (int it = 0; it < 16; ++it) {
      int j0 = w * 4096 + (it * 64 + lane) * 4;
      float4 p0 = *(const float4*)&pb[3 * j0];
      float4 p1 = *(const float4*)&pb[3 * j0 + 4];
      float4 p2 = *(const float4*)&pb[3 * j0 + 8];
      D2_PUSH(p0.x, p0.y, p0.z, j0)
      D2_PUSH(p0.w, p1.x, p1.y, j0 + 1)
      D2_PUSH(p1.z, p1.w, p2.x, j0 + 2)
      D2_PUSH(p2.y, p2.z, p2.w, j0 + 3)
    }
  }
  __syncthreads();
  // exact top-17 by (d2, idx) key — identical semantics to jax.lax.top_k
  if (w == 0) {
    int cnt = s_cnt;
    if (cnt > 192) cnt = 192;
    unsigned long long c0 = (lane < cnt) ? s_cand[lane] : ~0ULL;
    unsigned long long c1 = (lane + 64 < cnt) ? s_cand[lane + 64] : ~0ULL;
    unsigned long long c2 = (lane + 128 < cnt) ? s_cand[lane + 128] : ~0ULL;
    for (int it = 0; it < 17; ++it) {
      unsigned long long l01 = c0 < c1 ? c0 : c1;
      unsigned long long lo = l01 < c2 ? l01 : c2;
      unsigned long long mn = wave_min_u64(lo);
      if (lane == 0) s_knn[it] = (unsigned)mn;
      if (c0 == mn) c0 = ~0ULL;
      else if (c1 == mn) c1 = ~0ULL;
      else if (c2 == mn) c2 = ~0ULL;
    }
  }
  __syncthreads();

  // logits: wave w handles neighbors w*4 .. w*4+3 (same per-wave butterfly
  // summation as the verified R1 kernel -> bit-identical logits)
#pragma unroll
  for (int kk = 0; kk < 4; ++kk) {
    int k = w * 4 + kk;
    unsigned nb = s_knn[k + 1];
    const float* fp = feats + ((size_t)b * N_ + nb) * 128;
    float pr = s_g[lane] * fp[lane] + s_g[lane + 64] * fp[lane + 64];
    float ssum = wave_sum(pr);
    if (lane == 0) s_logit[k] = ssum;
  }
  __syncthreads();
  if (t == 0) {
    const float* gbp = gumb + (((size_t)b) * M_ + mm) * K_;
    float qb = s_qb;
    float bestv = -FLT_MAX;
    int bestn = (int)s_knn[1];
    for (int k = 0; k < 16; ++k) {
      float logit = (s_logit[k] + qb) / sqrtf(128.0f);
      float tot = (logit + gbp[k]) / 0.1f;
      if (tot > bestv) { bestv = tot; bestn = (int)s_knn[k + 1]; }
    }
    s_bestn = bestn;
    idxbuf[g] = bestn;
  }
  __syncthreads();
  if (t < 128) {
    int bn = s_bestn;
    walks[(size_t)g * 768 + (size_t)(l + 1) * 128 + t] =
        feats[((size_t)b * N_ + bn) * 128 + t];
  }
}

// ---------------- route + predict + scatter ----------------
// 256 threads: thread = (channel c, row-half). LDS aliased: 5 x 768 buffers.
__global__ __launch_bounds__(256) void k_route(
    const float* __restrict__ curr, const float* __restrict__ prev,
    float* __restrict__ outw, const float* __restrict__ w_in,
    const float* __restrict__ b_in, const float* __restrict__ w_out,
    const float* __restrict__ b_out, const float* __restrict__ rt_w1,
    const float* __restrict__ rt_b1, const float* __restrict__ rt_w2,
    const float* __restrict__ rt_b2, const float* __restrict__ pw1,
    const float* __restrict__ pb1, const float* __restrict__ pw2,
    const float* __restrict__ pb2, const int* __restrict__ start,
    float* __restrict__ pos) {
  __shared__ __align__(16) float sA[768];  // curr  -> attn@V output
  __shared__ __align__(16) float sB[768];  // prev  -> out-proj output
  __shared__ __align__(16) float sQ[768];  // q     -> relu(rt1)
  __shared__ __align__(16) float sK[768];  // k     -> final walks
  __shared__ __align__(16) float sV[768];  // v
  __shared__ __align__(16) float s_att[144];
  __shared__ __align__(16) float s_x[256];
  __shared__ __align__(16) float s_hid[64];

  int g = blockIdx.x, t = threadIdx.x;
  int b = g >> 9;
  int c = t & 127, half = t >> 7, r0 = half * 3;
  const float* cg = curr + (size_t)g * 768;
  const float* pg = prev + (size_t)g * 768;
  for (int i = t; i < 768; i += 256) {
    sA[i] = cg[i];
    sB[i] = pg[i];
  }
  __syncthreads();

  // QKV: thread (c, half) computes rows r0..r0+2 of channel c
  float aq[3], ak[3], av[3];
#pragma unroll
  for (int l = 0; l < 3; ++l) {
    aq[l] = b_in[c];
    ak[l] = b_in[128 + c];
    av[l] = b_in[256 + c];
  }
  for (int j = 0; j < 128; j += 4) {
    float4 wq = *(const float4*)&w_in[(size_t)c * 128 + j];
    float4 wk = *(const float4*)&w_in[(size_t)(128 + c) * 128 + j];
    float4 wv = *(const float4*)&w_in[(size_t)(256 + c) * 128 + j];
#pragma unroll
    for (int l = 0; l < 3; ++l) {
      float4 c4 = *(const float4*)&sA[(r0 + l) * 128 + j];
      float4 p4 = *(const float4*)&sB[(r0 + l) * 128 + j];
      aq[l] += wq.x * c4.x + wq.y * c4.y + wq.z * c4.z + wq.w * c4.w;
      ak[l] += wk.x * p4.x + wk.y * p4.y + wk.z * p4.z + wk.w * p4.w;
      av[l] += wv.x * p4.x + wv.y * p4.y + wv.z * p4.z + wv.w * p4.w;
    }
  }
#pragma unroll
  for (int l = 0; l < 3; ++l) {
    sQ[(r0 + l) * 128 + c] = aq[l];
    sK[(r0 + l) * 128 + c] = ak[l];
    sV[(r0 + l) * 128 + c] = av[l];
  }
  __syncthreads();

  // scores (144 = 4 heads x 6 x 6)
  if (t < 144) {
    int h = t / 36, r = t % 36, i = r / 6, jj = r % 6;
    float acc = 0.f;
#pragma unroll
    for (int d = 0; d < 32; d += 4) {
      float4 q4 = *(const float4*)&sQ[i * 128 + h * 32 + d];
      float4 k4 = *(const float4*)&sK[jj * 128 + h * 32 + d];
      acc += q4.x * k4.x + q4.y * k4.y + q4.z * k4.z + q4.w * k4.w;
    }
    s_att[t] = acc / sqrtf(32.0f);
  }
  __syncthreads();
  if (t < 24) {
    int h = t / 6, i = t % 6;
    int base = h * 36 + i * 6;
    float mx = s_att[base];
#pragma unroll
    for (int jj = 1; jj < 6; ++jj) mx = fmaxf(mx, s_att[base + jj]);
    float ex[6];
    float sum = 0.f;
#pragma unroll
    for (int jj = 0; jj < 6; ++jj) {
      ex[jj] = expf(s_att[base + jj] - mx);
      sum += ex[jj];
    }
#pragma unroll
    for (int jj = 0; jj < 6; ++jj) s_att[base + jj] = ex[jj] / sum;
  }
  __syncthreads();
  // attn @ V -> sA
  {
    int h = c >> 5;
    float o[3];
#pragma unroll
    for (int l = 0; l < 3; ++l) {
      float acc = 0.f;
#pragma unroll
      for (int jj = 0; jj < 6; ++jj)
        acc += s_att[h * 36 + (r0 + l) * 6 + jj] * sV[jj * 128 + c];
      o[l] = acc;
    }
#pragma unroll
    for (int l = 0; l < 3; ++l) sA[(r0 + l) * 128 + c] = o[l];
  }
  __syncthreads();

  // out-proj -> sB
  float ao[3];
#pragma unroll
  for (int l = 0; l < 3; ++l) ao[l] = b_out[c];
  for (int j = 0; j < 128; j += 4) {
    float4 w4 = *(const float4*)&w_out[(size_t)c * 128 + j];
#pragma unroll
    for (int l = 0; l < 3; ++l) {
      float4 o4 = *(const float4*)&sA[(r0 + l) * 128 + j];
      ao[l] += w4.x * o4.x + w4.y * o4.y + w4.z * o4.z + w4.w * o4.w;
    }
  }
#pragma unroll
  for (int l = 0; l < 3; ++l) sB[(r0 + l) * 128 + c] = ao[l];
  __syncthreads();

  // rt1 + relu -> sQ
  float a1[3];
#pragma unroll
  for (int l = 0; l < 3; ++l) a1[l] = rt_b1[c];
  for (int j = 0; j < 128; j += 4) {
    float4 w4 = *(const float4*)&rt_w1[(size_t)c * 128 + j];
#pragma unroll
    for (int l = 0; l < 3; ++l) {
      float4 o4 = *(const float4*)&sB[(r0 + l) * 128 + j];
      a1[l] += w4.x * o4.x + w4.y * o4.y + w4.z * o4.z + w4.w * o4.w;
    }
  }
#pragma unroll
  for (int l = 0; l < 3; ++l) sQ[(r0 + l) * 128 + c] = fmaxf(a1[l], 0.f);
  __syncthreads();

  // rt2 -> sK + global out
  float a2[3];
#pragma unroll
  for (int l = 0; l < 3; ++l) a2[l] = rt_b2[c];
  for (int j = 0; j < 128; j += 4) {
    float4 w4 = *(const float4*)&rt_w2[(size_t)c * 128 + j];
#pragma unroll
    for (int l = 0; l < 3; ++l) {
      float4 o4 = *(const float4*)&sQ[(r0 + l) * 128 + j];
      a2[l] += w4.x * o4.x + w4.y * o4.y + w4.z * o4.z + w4.w * o4.w;
    }
  }
  float* og = outw + (size_t)g * 768;
#pragma unroll
  for (int l = 0; l < 3; ++l) {
    og[(r0 + l) * 128 + c] = a2[l];
    sK[(r0 + l) * 128 + c] = a2[l];
  }
  __syncthreads();

  // predict
  if (half == 0) {
    float sm = 0.f;
#pragma unroll
    for (int l = 1; l < 6; ++l) sm += sK[l * 128 + c];
    s_x[c] = sm / 5.0f - sK[c];
    s_x[128 + c] = sK[c];
  }
  __syncthreads();
  if (t < 64) {
    float acc = pb1[t];
#pragma unroll
    for (int j = 0; j < 256; j += 4) {
      float4 w4 = *(const float4*)&pw1[(size_t)t * 256 + j];
      float4 x4 = *(const float4*)&s_x[j];
      acc += w4.x * x4.x + w4.y * x4.y + w4.z * x4.z + w4.w * x4.w;
    }
    s_hid[t] = fmaxf(acc, 0.f);
  }
  __syncthreads();
  if (t < 3) {
    float acc = pb2[t];
#pragma unroll
    for (int j = 0; j < 64; ++j) acc += pw2[t * 64 + j] * s_hid[j];
    float d = tanhf(acc);
    int s = start[g];
    atomicAdd(&pos[((size_t)b * N_ + s) * 3 + t], d);
  }
}

// ---------------- launcher ----------------
extern "C" void kernel_launch(void* const* d_in, const int* in_sizes, int n_in,
                              void* d_out, int out_size, void* d_ws,
                              size_t ws_size, hipStream_t stream) {
  const float* xyz = (const float*)d_in[0];
  const int* start = (const int*)d_in[1];
  const float* gumbel = (const float*)d_in[2];
  const float* enc_w1 = (const float*)d_in[3];
  const float* enc_b1 = (const float*)d_in[4];
  const float* enc_w2 = (const float*)d_in[5];
  const float* enc_b2 = (const float*)d_in[6];
  const float* beta_w = (const float*)d_in[7];
  const float* beta_b = (const float*)d_in[8];
  const float* gamma_w = (const float*)d_in[9];
  const float* gamma_b = (const float*)d_in[10];
  const float* attn_w_in = (const float*)d_in[11];
  const float* attn_b_in = (const float*)d_in[12];
  const float* attn_w_out = (const float*)d_in[13];
  const float* attn_b_out = (const float*)d_in[14];
  const float* rt_w1 = (const float*)d_in[15];
  const float* rt_b1 = (const float*)d_in[16];
  const float* rt_w2 = (const float*)d_in[17];
  const float* rt_b2 = (const float*)d_in[18];
  const float* pred_w1 = (const float*)d_in[19];
  const float* pred_b1 = (const float*)d_in[20];
  const float* pred_w2 = (const float*)d_in[21];
  const float* pred_b2 = (const float*)d_in[22];

  float* pos = (float*)d_out;
  float* ws = (float*)d_ws;
  float* feats = ws;                                   // 32MB
  float* wsel = feats + (size_t)B_ * N_ * C_;          // 6MB
  float* wA = wsel + (size_t)B_ * M_ * L_ * C_;        // 6MB
  float* wB = wA + (size_t)B_ * M_ * L_ * C_;          // 6MB
  int* idxbuf = (int*)(wB + (size_t)B_ * M_ * L_ * C_);

  hipMemcpyAsync(pos, xyz, (size_t)B_ * N_ * 3 * sizeof(float),
                 hipMemcpyDeviceToDevice, stream);
  k_encode<<<2048, 256, 0, stream>>>(xyz, enc_w1, enc_b1, enc_w2, enc_b2,
                                     feats);

  float* prevbuf = wsel;
  for (int t = 0; t < STEPS_; ++t) {
    k_step_init<<<2048, 128, 0, stream>>>(feats, start, idxbuf, wsel);
    for (int l = 0; l < L_ - 1; ++l) {
      const float* gptr =
          gumbel + (size_t)(t * (L_ - 1) + l) * B_ * M_ * K_;
      k_select<<<2048, 256, 0, stream>>>(pos, feats, idxbuf, wsel, beta_w,
                                         beta_b, gamma_w, gamma_b, gptr, l);
    }
    float* ob = (t & 1) ? wB : wA;
    k_route<<<2048, 256, 0, stream>>>(
        wsel, prevbuf, ob, attn_w_in, attn_b_in, attn_w_out, attn_b_out, rt_w1,
        rt_b1, rt_w2, rt_b2, pred_w1, pred_b1, pred_w2, pred_b2, start, pos);
    prevbuf = ob;
  }
}